// Round 1
// baseline (445.681 us; speedup 1.0000x reference)
//
#include <hip/hip_runtime.h>

#define NN 4096
#define EE 65536
#define HC 256   // hidden channels

typedef unsigned short ushort_t;
typedef __attribute__((ext_vector_type(8))) short bf16x8;
typedef __attribute__((ext_vector_type(4))) float f32x4;

__device__ __forceinline__ ushort_t f2bf(float f) {
    unsigned int u = __float_as_uint(f);
    unsigned int r = (u + 0x7fffu + ((u >> 16) & 1u)) >> 16;
    return (ushort_t)r;
}
__device__ __forceinline__ float bf2f(ushort_t u) {
    return __uint_as_float(((unsigned int)u) << 16);
}
// pack two floats to bf16 pair (round-half-up), a in low 16 (lower address)
__device__ __forceinline__ unsigned int pack2bf(float a, float b) {
    unsigned int ua = __float_as_uint(a) + 0x8000u;
    unsigned int ub = __float_as_uint(b) + 0x8000u;
    return __builtin_amdgcn_perm(ub, ua, 0x07060302u);
}

// ---------------- degree / CSR build ----------------
__global__ void deg_init_k(float* __restrict__ deg) {
    int i = blockIdx.x * 256 + threadIdx.x;
    deg[i] = 1.0f;  // self loop
}
__global__ void deg_scatter_k(const int* __restrict__ dst, float* __restrict__ deg) {
    int e = blockIdx.x * 256 + threadIdx.x;
    atomicAdd(&deg[dst[e]], 1.0f);
}
__global__ void dinv_k(const float* __restrict__ deg, float* __restrict__ dinv) {
    int i = blockIdx.x * 256 + threadIdx.x;
    dinv[i] = rsqrtf(deg[i]);
}
__global__ __launch_bounds__(1024)
void scan_offsets_k(const float* __restrict__ deg, int* __restrict__ offs,
                    int* __restrict__ cursor) {
    __shared__ int part[1024];
    const int t = threadIdx.x;
    int c0 = (int)deg[t * 4 + 0] - 1;
    int c1 = (int)deg[t * 4 + 1] - 1;
    int c2 = (int)deg[t * 4 + 2] - 1;
    int c3 = (int)deg[t * 4 + 3] - 1;
    part[t] = c0 + c1 + c2 + c3;
    __syncthreads();
    for (int off = 1; off < 1024; off <<= 1) {
        int v = (t >= off) ? part[t - off] : 0;
        __syncthreads();
        part[t] += v;
        __syncthreads();
    }
    int base = (t == 0) ? 0 : part[t - 1];
    offs[t * 4 + 0] = base;
    offs[t * 4 + 1] = base + c0;
    offs[t * 4 + 2] = base + c0 + c1;
    offs[t * 4 + 3] = base + c0 + c1 + c2;
    cursor[t * 4 + 0] = base;
    cursor[t * 4 + 1] = base + c0;
    cursor[t * 4 + 2] = base + c0 + c1;
    cursor[t * 4 + 3] = base + c0 + c1 + c2;
    if (t == 1023) offs[4096] = part[1023];
}
__global__ void csr_fill_k(const int* __restrict__ src, const int* __restrict__ dst,
                           int* __restrict__ cursor, int* __restrict__ csr_src) {
    int e = blockIdx.x * 256 + threadIdx.x;
    int pos = atomicAdd(&cursor[dst[e]], 1);
    csr_src[pos] = src[e];
}

// ---------------- GCN gather ----------------
__global__ __launch_bounds__(256)
void gcn_gather_k(const float* __restrict__ xw, const float* __restrict__ dinv,
                  const int* __restrict__ offs, const int* __restrict__ csr_src,
                  float* __restrict__ agg) {
    const int node = blockIdx.x * 4 + (threadIdx.x >> 6);
    const int c = (threadIdx.x & 63) * 4;
    const float dd = dinv[node];
    float4 a = *(const float4*)&xw[(size_t)node * HC + c];
    const float self = dd * dd;
    float4 acc = make_float4(a.x * self, a.y * self, a.z * self, a.w * self);
    const int beg = offs[node], end = offs[node + 1];
    for (int e = beg; e < end; e++) {
        int s = csr_src[e];
        float coef = dinv[s] * dd;
        const float4 v = *(const float4*)&xw[(size_t)s * HC + c];
        acc.x += v.x * coef;
        acc.y += v.y * coef;
        acc.z += v.z * coef;
        acc.w += v.w * coef;
    }
    *(float4*)&agg[(size_t)node * HC + c] = acc;
}

// ---------------- fp32 -> bf16 convert ----------------
__global__ void cvt_bf16_k(const float* __restrict__ in, ushort_t* __restrict__ out) {
    int i = (blockIdx.x * 256 + threadIdx.x) * 4;
    float4 v = *(const float4*)&in[i];
    unsigned int d0 = pack2bf(v.x, v.y), d1 = pack2bf(v.z, v.w);
    *(uint2*)&out[i] = make_uint2(d0, d1);
}

// ---------------- bf16-MFMA GEMM, 64row x 32col tile (2 blocks/CU+), dual region ----
__global__ __launch_bounds__(256)
void gemm_bf_k(const float* __restrict__ X, const float* __restrict__ W,
               const float* __restrict__ bias1, const float* __restrict__ bias2,
               const float* __restrict__ res1, const float* __restrict__ res2, float res2scale,
               float* __restrict__ out, int K, int M, int dorelu, int obf,
               int colsplit, const float* __restrict__ W2,
               const float* __restrict__ bias_r2, float* __restrict__ out2, int M2)
{
    __shared__ ushort_t As[64][72];
    __shared__ ushort_t Bs[32][72];
    const int t = threadIdx.x;
    const int w = t >> 6, lane = t & 63;
    const int m = lane & 15, quad = lane >> 4;
    const int row0 = blockIdx.y << 6, col0 = blockIdx.x << 5;   // 32-col tiles
    const int sr = t >> 2;
    const int sc = (t & 3) << 4;
    const int wr2 = t >> 3;           // W staging row 0..31
    const int wc2 = (t & 7) << 3;     // W staging k-chunk 0,8,...,56

    const float* Wu = W;
    const float* b1u = bias1;
    const float* b2u = bias2;
    float* outu = out;
    int Mu = M, colu = col0;
    if (colsplit > 0 && col0 >= colsplit) {
        Wu = W2; b1u = bias_r2; b2u = nullptr;
        outu = out2; Mu = M2; colu = col0 - colsplit;
    }

    f32x4 acc[2] = {};
    for (int k0 = 0; k0 < K; k0 += 64) {
        const float* xp = &X[(size_t)(row0 + sr) * K + k0 + sc];
        const float* wp = &Wu[(size_t)(colu + wr2) * K + k0 + wc2];
        float4 xa = *(const float4*)xp,       xb = *(const float4*)(xp + 4);
        float4 xc = *(const float4*)(xp + 8), xd = *(const float4*)(xp + 12);
        float4 wa = *(const float4*)wp,       wb = *(const float4*)(wp + 4);
        __syncthreads();
        {
            unsigned int tx[8];
            tx[0] = pack2bf(xa.x, xa.y); tx[1] = pack2bf(xa.z, xa.w);
            tx[2] = pack2bf(xb.x, xb.y); tx[3] = pack2bf(xb.z, xb.w);
            tx[4] = pack2bf(xc.x, xc.y); tx[5] = pack2bf(xc.z, xc.w);
            tx[6] = pack2bf(xd.x, xd.y); tx[7] = pack2bf(xd.z, xd.w);
            *(uint4*)&As[sr][sc]     = *(const uint4*)&tx[0];
            *(uint4*)&As[sr][sc + 8] = *(const uint4*)&tx[4];
            unsigned int tw[4];
            tw[0] = pack2bf(wa.x, wa.y); tw[1] = pack2bf(wa.z, wa.w);
            tw[2] = pack2bf(wb.x, wb.y); tw[3] = pack2bf(wb.z, wb.w);
            *(uint4*)&Bs[wr2][wc2] = *(const uint4*)&tw[0];
        }
        __syncthreads();
        #pragma unroll
        for (int kc = 0; kc < 2; kc++) {
            bf16x8 af = *(const bf16x8*)&As[(w << 4) + m][kc * 32 + quad * 8];
            #pragma unroll
            for (int cb = 0; cb < 2; cb++) {
                bf16x8 bf = *(const bf16x8*)&Bs[cb * 16 + m][kc * 32 + quad * 8];
                acc[cb] = __builtin_amdgcn_mfma_f32_16x16x32_bf16(af, bf, acc[cb], 0, 0, 0);
            }
        }
    }
    #pragma unroll
    for (int cb = 0; cb < 2; cb++) {
        #pragma unroll
        for (int r = 0; r < 4; r++) {
            const int row = row0 + (w << 4) + quad * 4 + r;
            const int col = colu + cb * 16 + m;
            float v = acc[cb][r];
            if (b1u) v += b1u[col];
            if (b2u) v += b2u[col];
            if (res1) v += res1[(size_t)row * Mu + col];
            if (res2) v += res2scale * res2[(size_t)row * Mu + col];
            if (dorelu) v = fmaxf(v, 0.f);
            if (obf) ((ushort_t*)outu)[(size_t)row * Mu + col] = f2bf(v);
            else outu[(size_t)row * Mu + col] = v;
        }
    }
}

// ---------------- K/V bf16 prep: Kb[h][n][d], Vtb[h][d][n] ----------------
__global__ __launch_bounds__(256)
void kv_prep_k(const float* __restrict__ qkv, ushort_t* __restrict__ Kb,
               ushort_t* __restrict__ Vtb)
{
    __shared__ ushort_t Vs[64][72];
    const int h = blockIdx.y;
    const int n0 = blockIdx.x << 6;
    const int t = threadIdx.x;
    for (int u = t; u < 1024; u += 256) {
        int r = u >> 4, c = u & 15;
        const float* kp = &qkv[(size_t)(n0 + r) * 768 + 256 + h * 64 + c * 4];
        float4 kv = *(const float4*)kp;
        float4 vv = *(const float4*)(kp + 256);
        *(uint2*)&Kb[((size_t)(h * 4096 + n0 + r)) * 64 + c * 4] =
            make_uint2(pack2bf(kv.x, kv.y), pack2bf(kv.z, kv.w));
        *(uint2*)&Vs[r][c * 4] =
            make_uint2(pack2bf(vv.x, vv.y), pack2bf(vv.z, vv.w));
    }
    __syncthreads();
    int d = t >> 2, kc = t & 3;
    __attribute__((aligned(16))) ushort_t vals[16];
    #pragma unroll
    for (int k = 0; k < 16; k++) vals[k] = Vs[kc * 16 + k][d];
    ushort_t* op = &Vtb[((size_t)(h * 64 + d)) * 4096 + n0 + kc * 16];
    *(uint4*)op = *(const uint4*)&vals[0];
    *(uint4*)(op + 8) = *(const uint4*)&vals[8];
}

// ---------------- split-K MFMA flash attention partials (exp2 domain) ----------------
// v2: T14 async staging (reg-prefetch next K/V tile under current compute),
//     T13 defer-max (skip alpha rescale unless any row max grows > 8 in log2),
//     T5 setprio around MFMA clusters, hoisted staging address math.
__global__ __launch_bounds__(256)
void attn_part_k(const float* qkv, const ushort_t* __restrict__ Kb,
                 const ushort_t* __restrict__ Vtb, ushort_t* opart,
                 float* __restrict__ m_part, float* __restrict__ l_part)
{
    __shared__ ushort_t Kt[64][72];
    __shared__ ushort_t Vt[64][72];
    __shared__ ushort_t Plb[4][16][72];
    const int h = blockIdx.y & 3;
    const int split = blockIdx.y >> 2;
    const int q0 = blockIdx.x << 6;
    const int t = threadIdx.x;
    const int w = t >> 6, lane = t & 63;
    const int m = lane & 15, quad = lane >> 4;

    // ---- hoisted staging geometry: thread covers rows r0 and r0+32, 16B col chunk
    const int r0 = t >> 3, c8 = (t & 7) << 3;
    const int r1 = r0 + 32;
    const int pr0 = ((r0 & 15) << 2) | (r0 >> 4);   // permuted key row for Kt
    const int pr1 = ((r1 & 15) << 2) | (r1 >> 4);
    const ushort_t* kb_p0 = &Kb[((size_t)(h * 4096 + split * 1024 + pr0)) * 64 + c8];
    const ushort_t* kb_p1 = &Kb[((size_t)(h * 4096 + split * 1024 + pr1)) * 64 + c8];
    const ushort_t* vt_p0 = &Vtb[((size_t)(h * 64 + r0)) * 4096 + split * 1024 + c8];
    const ushort_t* vt_p1 = &Vtb[((size_t)(h * 64 + r1)) * 4096 + split * 1024 + c8];
    ushort_t* const kt_d0 = &Kt[r0][c8];
    ushort_t* const kt_d1 = &Kt[r1][c8];
    ushort_t* const vt_d0 = &Vt[r0][c8];
    ushort_t* const vt_d1 = &Vt[r1][c8];

    // Q prescaled by 0.125*log2(e): scores land in log2 domain
    const float qs = 0.125f * 1.44269504f;
    bf16x8 qf[2];
    #pragma unroll
    for (int kc = 0; kc < 2; kc++) {
        const float* qp = &qkv[(size_t)(q0 + w * 16 + m) * 768 + h * 64 + kc * 32 + quad * 8];
        float4 a = *(const float4*)qp;
        float4 b = *(const float4*)(qp + 4);
        qf[kc][0] = (short)f2bf(a.x * qs);
        qf[kc][1] = (short)f2bf(a.y * qs);
        qf[kc][2] = (short)f2bf(a.z * qs);
        qf[kc][3] = (short)f2bf(a.w * qs);
        qf[kc][4] = (short)f2bf(b.x * qs);
        qf[kc][5] = (short)f2bf(b.y * qs);
        qf[kc][6] = (short)f2bf(b.z * qs);
        qf[kc][7] = (short)f2bf(b.w * qs);
    }
    bf16x8 onesf;
    #pragma unroll
    for (int j = 0; j < 8; j++) onesf[j] = (short)0x3F80;

    f32x4 o[4], ol;
    float mrow[4];
    #pragma unroll
    for (int i = 0; i < 4; i++) {
        o[i] = (f32x4){0.f, 0.f, 0.f, 0.f};
        mrow[i] = -1e30f;
    }
    ol = (f32x4){0.f, 0.f, 0.f, 0.f};

    // prologue: issue first tile's loads
    uint4 kr0 = *(const uint4*)kb_p0;
    uint4 kr1 = *(const uint4*)kb_p1;
    uint4 vr0 = *(const uint4*)vt_p0;
    uint4 vr1 = *(const uint4*)vt_p1;

    for (int it = 0; it < 16; it++) {
        __syncthreads();                 // previous tile's compute done, LDS free
        *(uint4*)kt_d0 = kr0;            // write-late: staged regs -> LDS
        *(uint4*)kt_d1 = kr1;
        *(uint4*)vt_d0 = vr0;
        *(uint4*)vt_d1 = vr1;
        if (it < 15) {                   // issue-early: next tile flies under compute
            kb_p0 += 4096; kb_p1 += 4096; vt_p0 += 64; vt_p1 += 64;
            kr0 = *(const uint4*)kb_p0;
            kr1 = *(const uint4*)kb_p1;
            vr0 = *(const uint4*)vt_p0;
            vr1 = *(const uint4*)vt_p1;
        }
        __syncthreads();

        f32x4 s[4];
        #pragma unroll
        for (int b = 0; b < 4; b++) s[b] = (f32x4){0.f, 0.f, 0.f, 0.f};
        __builtin_amdgcn_s_setprio(1);
        #pragma unroll
        for (int b = 0; b < 4; b++)
            #pragma unroll
            for (int kc = 0; kc < 2; kc++) {
                bf16x8 kf = *(const bf16x8*)&Kt[b * 16 + m][kc * 32 + quad * 8];
                s[b] = __builtin_amdgcn_mfma_f32_16x16x32_bf16(qf[kc], kf, s[b], 0, 0, 0);
            }
        __builtin_amdgcn_s_setprio(0);

        // row max (uniform across the 16 m-lanes after the butterfly)
        float mx[4];
        #pragma unroll
        for (int r = 0; r < 4; r++) {
            float v = fmaxf(fmaxf(s[0][r], s[1][r]), fmaxf(s[2][r], s[3][r]));
            #pragma unroll
            for (int off = 1; off < 16; off <<= 1)
                v = fmaxf(v, __shfl_xor(v, off));
            mx[r] = v;
        }
        // T13 defer-max: only rescale when some row's max grew by > 8 (log2)
        bool grow = (mx[0] > mrow[0] + 8.f) | (mx[1] > mrow[1] + 8.f) |
                    (mx[2] > mrow[2] + 8.f) | (mx[3] > mrow[3] + 8.f);
        if (__any(grow)) {
            #pragma unroll
            for (int r = 0; r < 4; r++) {
                float mn = fmaxf(mrow[r], mx[r]);
                float alpha = __builtin_amdgcn_exp2f(mrow[r] - mn);
                mrow[r] = mn;
                o[0][r] *= alpha; o[1][r] *= alpha;
                o[2][r] *= alpha; o[3][r] *= alpha;
                ol[r] *= alpha;
            }
        }
        #pragma unroll
        for (int r = 0; r < 4; r++) {
            unsigned int d0 = pack2bf(__builtin_amdgcn_exp2f(s[0][r] - mrow[r]),
                                      __builtin_amdgcn_exp2f(s[1][r] - mrow[r]));
            unsigned int d1 = pack2bf(__builtin_amdgcn_exp2f(s[2][r] - mrow[r]),
                                      __builtin_amdgcn_exp2f(s[3][r] - mrow[r]));
            *(uint2*)&Plb[w][quad * 4 + r][m * 4] = make_uint2(d0, d1);
        }

        __builtin_amdgcn_s_setprio(1);
        #pragma unroll
        for (int kc = 0; kc < 2; kc++) {
            bf16x8 pa = *(const bf16x8*)&Plb[w][m][kc * 32 + quad * 8];
            #pragma unroll
            for (int nb = 0; nb < 4; nb++) {
                bf16x8 vf = *(const bf16x8*)&Vt[nb * 16 + m][kc * 32 + quad * 8];
                o[nb] = __builtin_amdgcn_mfma_f32_16x16x32_bf16(pa, vf, o[nb], 0, 0, 0);
            }
            ol = __builtin_amdgcn_mfma_f32_16x16x32_bf16(pa, onesf, ol, 0, 0, 0);
        }
        __builtin_amdgcn_s_setprio(0);
    }

    #pragma unroll
    for (int nb = 0; nb < 4; nb++)
        #pragma unroll
        for (int r = 0; r < 4; r++) {
            int q = q0 + w * 16 + quad * 4 + r;
            opart[(size_t)q * 1536 + 512 + split * 256 + h * 64 + nb * 16 + m] = f2bf(o[nb][r]);
        }
    if (m == 0) {
        #pragma unroll
        for (int r = 0; r < 4; r++) {
            int q = q0 + w * 16 + quad * 4 + r;
            m_part[(split * 4 + h) * 4096 + q] = mrow[r];
            l_part[(split * 4 + h) * 4096 + q] = ol[r];
        }
    }
}

// merge 4 splits (m in log2 domain)
__global__ __launch_bounds__(256)
void attn_merge_k(const ushort_t* __restrict__ opart, const float* __restrict__ m_part,
                  const float* __restrict__ l_part, float* __restrict__ att)
{
    int idx = blockIdx.x * 256 + threadIdx.x;
    int q = idx >> 8, c = idx & 255;
    int h = c >> 6, d = c & 63;
    float ms[4];
    float mmax = -1e30f;
    #pragma unroll
    for (int s = 0; s < 4; s++) {
        ms[s] = m_part[(s * 4 + h) * 4096 + q];
        mmax = fmaxf(mmax, ms[s]);
    }
    float onum = 0.f, lden = 0.f;
    #pragma unroll
    for (int s = 0; s < 4; s++) {
        float wgt = __builtin_amdgcn_exp2f(ms[s] - mmax);
        float ov = bf2f(opart[(size_t)q * 1536 + 512 + s * 256 + h * 64 + d]);
        onum += wgt * ov;
        lden += wgt * l_part[(s * 4 + h) * 4096 + q];
    }
    att[(size_t)q * 256 + c] = onum / lden;
}

// ---------------- symmetrized final MLP, MFMA bf16 ----------------
__global__ __launch_bounds__(256)
void sym_mlp_mfma_k(const ushort_t* __restrict__ Tb, const ushort_t* __restrict__ Wb,
                    const float* __restrict__ b2, float* __restrict__ out)
{
    __shared__ ushort_t As[128][72];
    __shared__ ushort_t Bs[128][72];
    const int t = threadIdx.x;
    const int w = t >> 6, lane = t & 63;
    const int m = lane & 15, quad = lane >> 4;
    const int wr = (w >> 1) * 64, wc = (w & 1) * 64;
    const int ri = blockIdx.y * 128, rj = blockIdx.x * 128;

    f32x4 acc[4][4] = {};
    for (int kk = 0; kk < 8; kk++) {
        const int k0 = kk * 64;
        const ushort_t* Asrc = (k0 < 256) ? Tb : Wb;
        const ushort_t* Bsrc = (k0 < 256) ? Wb : Tb;
        const int kcol = k0 & 255;
        __syncthreads();
        #pragma unroll
        for (int i = 0; i < 4; i++) {
            int s = t + i * 256;
            int row = s >> 3, ch = (s & 7) * 8;
            *(uint4*)&As[row][ch] = *(const uint4*)&Asrc[(size_t)(ri + row) * 256 + kcol + ch];
            *(uint4*)&Bs[row][ch] = *(const uint4*)&Bsrc[(size_t)(rj + row) * 256 + kcol + ch];
        }
        __syncthreads();
        #pragma unroll
        for (int kc = 0; kc < 2; kc++) {
            bf16x8 af[4], bfr[4];
            #pragma unroll
            for (int rb = 0; rb < 4; rb++)
                af[rb] = *(const bf16x8*)&As[wr + rb * 16 + m][kc * 32 + quad * 8];
            #pragma unroll
            for (int cb = 0; cb < 4; cb++)
                bfr[cb] = *(const bf16x8*)&Bs[wc + cb * 16 + m][kc * 32 + quad * 8];
            #pragma unroll
            for (int rb = 0; rb < 4; rb++)
                #pragma unroll
                for (int cb = 0; cb < 4; cb++)
                    acc[rb][cb] = __builtin_amdgcn_mfma_f32_16x16x32_bf16(af[rb], bfr[cb], acc[rb][cb], 0, 0, 0);
        }
    }
    #pragma unroll
    for (int rb = 0; rb < 4; rb++) {
        #pragma unroll
        for (int r = 0; r < 4; r++) {
            const int gr = ri + wr + rb * 16 + quad * 4 + r;
            const float br = b2[gr];
            #pragma unroll
            for (int cb = 0; cb < 4; cb++) {
                const int gc = rj + wc + cb * 16 + m;
                out[(size_t)gr * NN + gc] = 0.5f * (acc[rb][cb][r] + br + b2[gc]);
            }
        }
    }
}

// ---------------- launch ----------------
extern "C" void kernel_launch(void* const* d_in, const int* in_sizes, int n_in,
                              void* d_out, int out_size, void* d_ws, size_t ws_size,
                              hipStream_t stream) {
    (void)in_sizes; (void)n_in; (void)out_size; (void)ws_size;
    const float* x = (const float*)d_in[0];
    const int* ei = (const int*)d_in[1];
    const int* src = ei;
    const int* dst = ei + EE;

    float* ws = (float*)d_ws;
    const int NH = NN * HC;          // 1,048,576 floats
    float* h0  = ws;
    float* hb  = ws + 1 * NH;
    float* hc  = ws + 2 * NH;
    float* att = ws + 3 * NH;
    float* qkv = ws + 4 * NH;
    float* ffh = ws + 4 * NH;        // reuses qkv region (dead by then)
    float* deg = ws + 7 * NH;
    float* dinv = deg + NN;
    int* offs    = (int*)(dinv + NN);
    int* cursor  = offs + 4100;
    int* csr_src = cursor + 4096;
    float* m_part = (float*)(csr_src + EE);
    float* l_part = m_part + 65536;
    ushort_t* Kb  = (ushort_t*)hc;
    ushort_t* Vtb = Kb + NH;
    ushort_t* Tb  = (ushort_t*)hb;
    ushort_t* W2b = Tb + NH;

    deg_init_k<<<NN / 256, 256, 0, stream>>>(deg);
    deg_scatter_k<<<EE / 256, 256, 0, stream>>>(dst, deg);
    dinv_k<<<NN / 256, 256, 0, stream>>>(deg, dinv);
    scan_offsets_k<<<1, 1024, 0, stream>>>(deg, offs, cursor);
    csr_fill_k<<<EE / 256, 256, 0, stream>>>(src, dst, cursor, csr_src);

    // pre: h0 = relu(x @ pre_w^T + pre_b)
    gemm_bf_k<<<dim3(8, 64), 256, 0, stream>>>(
        x, (const float*)d_in[2], (const float*)d_in[3], nullptr,
        nullptr, nullptr, 0.f, h0, 128, 256, 1, 0,
        0, nullptr, nullptr, nullptr, 0);

    for (int L = 0; L < 2; L++) {
        int B = 4 + L * 10;
        const float* gw = (const float*)d_in[B + 0];
        const float* gb = (const float*)d_in[B + 1];
        const float* iw = (const float*)d_in[B + 2];
        const float* ib = (const float*)d_in[B + 3];
        const float* ow = (const float*)d_in[B + 4];
        const float* ob = (const float*)d_in[B + 5];
        const float* w1 = (const float*)d_in[B + 6];
        const float* b1 = (const float*)d_in[B + 7];
        const float* w2 = (const float*)d_in[B + 8];
        const float* b2 = (const float*)d_in[B + 9];

        // fused: cols 0-255 = h0@gw^T -> att(xw); cols 256-1023 = h0@iw^T+ib -> qkv
        gemm_bf_k<<<dim3(32, 64), 256, 0, stream>>>(
            h0, gw, nullptr, nullptr, nullptr, nullptr, 0.f, att, 256, 256, 0, 0,
            256, iw, ib, qkv, 768);
        gcn_gather_k<<<NN / 4, 256, 0, stream>>>(att, dinv, offs, csr_src, hb);
        kv_prep_k<<<dim3(64, 4), 256, 0, stream>>>(qkv, Kb, Vtb);
        attn_part_k<<<dim3(64, 16), 256, 0, stream>>>(
            qkv, Kb, Vtb, (ushort_t*)qkv, m_part, l_part);
        attn_merge_k<<<NN, 256, 0, stream>>>(
            (const ushort_t*)qkv, m_part, l_part, att);
        gemm_bf_k<<<dim3(8, 64), 256, 0, stream>>>(
            att, ow, ob, gb, hb, h0, 2.0f, hc, 256, 256, 0, 0,
            0, nullptr, nullptr, nullptr, 0);
        gemm_bf_k<<<dim3(16, 64), 256, 0, stream>>>(
            hc, w1, b1, nullptr, nullptr, nullptr, 0.f, ffh, 256, 512, 1, 0,
            0, nullptr, nullptr, nullptr, 0);
        gemm_bf_k<<<dim3(8, 64), 256, 0, stream>>>(
            ffh, w2, b2, nullptr, hc, nullptr, 0.f, h0, 512, 256, 1, 0,
            0, nullptr, nullptr, nullptr, 0);
    }

    // Tb(bf16) = relu(h0 @ mlp_w1^T + mlp_b1)
    gemm_bf_k<<<dim3(8, 64), 256, 0, stream>>>(
        h0, (const float*)d_in[24], (const float*)d_in[25], nullptr,
        nullptr, nullptr, 0.f, (float*)Tb, 256, 256, 1, 1,
        0, nullptr, nullptr, nullptr, 0);
    // W2b = bf16(mlp_w2)
    cvt_bf16_k<<<NH / 1024, 256, 0, stream>>>((const float*)d_in[26], W2b);
    // out = 0.5*(delta + delta^T) via K=512 concat GEMM
    sym_mlp_mfma_k<<<dim3(32, 32), 256, 0, stream>>>(
        Tb, W2b, (const float*)d_in[27], (float*)d_out);
}